// Round 5
// baseline (100.810 us; speedup 1.0000x reference)
//
#include <hip/hip_runtime.h>
#include <hip/hip_bf16.h>
#include <math.h>

// FourierWeightLinear: out = x @ W + bias, W = Ta(1024x192) . Tb(1024x192)^T.
// Associativity: out = (x @ Ta) @ Tb^T  -- never materialize W.
//   u = ox*iv + oz*0.5 + phi;  iv(i)=jv(i)=(i+1)/1025 (exact f32 match to ref)
//   TaT[2t][i]=P, TaT[2t+1][i]=Q;  Tb[j][2t]=cos(oy*jv), Tb[j][2t+1]=sin(oy*jv)
// G1: Y[4096][192] = x @ Ta  (BM=16 -> 256 blocks, no split-K, fused cvt)
// G2: out = Y @ Tb^T + bias  (K=192, BK=64, dbuf)
// LDS tiles have 128B row stride -> 16-way bank conflict if linear; fixed by
// XOR-swizzle of the 16B chunk index (chunk ^= row&7), applied BOTH on the
// staging side (pre-swizzled global source for gload_lds / swizzled ds_write)
// and the read side (rule 21: both-sides-or-neither).

#define IN_DIM   1024
#define OUT_DIM  1024
#define NBANDS   96
#define KTAB     192
#define MX       4096
#define SCALE_W  0.03125f

typedef __bf16 bf16x8 __attribute__((ext_vector_type(8)));
typedef float  f32x4  __attribute__((ext_vector_type(4)));

#define AS1 __attribute__((address_space(1)))
#define AS3 __attribute__((address_space(3)))

__device__ __forceinline__ void gload_lds16(const void* g, void* l) {
  __builtin_amdgcn_global_load_lds((AS1 void*)(g), (AS3 void*)(l), 16, 0, 0);
}

__device__ __forceinline__ unsigned short bf16bits(float f) {
  __hip_bfloat16 b = __float2bfloat16(f);
  return *(unsigned short*)&b;
}

// ---------------- tables: 384 blocks (96 bands x 4 row-chunks) -----------
__global__ void build_tables(const float* __restrict__ omega,  // [96][3]
                             const float* __restrict__ phi,    // [96]
                             const float* __restrict__ alpha,  // [192]
                             __hip_bfloat16* __restrict__ TaT, // [192][1024]
                             __hip_bfloat16* __restrict__ Tb) {// [1024][192]
  const int t = blockIdx.x;
  const int i = blockIdx.y * 256 + threadIdx.x;     // 0..1023
  const float ox = omega[3 * t], oy = omega[3 * t + 1], oz = omega[3 * t + 2];
  const float uc = oz * 0.5f + phi[t];
  const float as_ = alpha[t], ac = alpha[NBANDS + t];
  const float coord = (float)(i + 1) / 1025.0f;     // == pos coords exactly
  float su, cu;
  sincosf(ox * coord + uc, &su, &cu);
  TaT[(size_t)(2 * t) * IN_DIM + i]     = __float2bfloat16(SCALE_W * (as_ * su + ac * cu));
  TaT[(size_t)(2 * t + 1) * IN_DIM + i] = __float2bfloat16(SCALE_W * (as_ * cu - ac * su));
  float sv, cv;
  sincosf(oy * coord, &sv, &cv);
  Tb[(size_t)i * KTAB + 2 * t]     = __float2bfloat16(cv);
  Tb[(size_t)i * KTAB + 2 * t + 1] = __float2bfloat16(sv);
}

// ---------------- G1: Y = x @ Ta, BM=16, BK=64, dbuf, swizzled LDS -------
// grid (256), 256 threads = 4 waves; wave w -> cols 48w..48w+47, acc[3].
__global__ __launch_bounds__(256)
void gemm_xta(const float* __restrict__ X,             // [4096][1024] f32
              const __hip_bfloat16* __restrict__ TaT,  // [192][1024]
              __hip_bfloat16* __restrict__ Y) {        // [4096][192]
  __shared__ __align__(16) __hip_bfloat16 As[2][16 * 64];
  __shared__ __align__(16) __hip_bfloat16 Bs[2][192 * 64];
  const int tid  = threadIdx.x;
  const int lane = tid & 63;
  const int wc   = tid >> 6;
  const int m0   = blockIdx.x * 16;
  const int lr = lane & 15;
  const int hi = lane >> 4;          // 0..3 -> k 16B-chunk within 32-elem half

  const float* xbase = X + (size_t)m0 * IN_DIM;

  f32x4 acc[3] = {};

  auto ALOAD = [&](int t, float4& a) {
    const int r = tid >> 4, c4 = tid & 15;   // 16 float4 per 64-f32 row
    a = *(const float4*)(xbase + (size_t)r * IN_DIM + t * 64 + c4 * 4);
  };
  auto AWRITE = [&](int buf, const float4& a) {
    const int r = tid >> 4, c4 = tid & 15;   // c4 = 8B-chunk index
    ushort4 o;
    o.x = bf16bits(a.x); o.y = bf16bits(a.y);
    o.z = bf16bits(a.z); o.w = bf16bits(a.w);
    const int byte = r * 128 + ((((c4 >> 1) ^ (r & 7)) << 4) | ((c4 & 1) << 3));
    *(ushort4*)((char*)&As[buf][0] + byte) = o;
  };
  auto BSTAGE = [&](int t, int buf) {
#pragma unroll
    for (int q = 0; q < 6; ++q) {
      const int f = q * 256 + tid;           // 1536 16B chunks, LDS linear
      const int r = f >> 3, g = f & 7;
      gload_lds16(TaT + (size_t)r * IN_DIM + t * 64 + ((g ^ (r & 7)) * 8),
                  (char*)&Bs[buf][0] + (size_t)f * 16);
    }
  };
  auto COMPUTE = [&](int buf) {
#pragma unroll
    for (int kk = 0; kk < 2; ++kk) {
      bf16x8 af, bfr[3];
      af = *(const bf16x8*)((char*)&As[buf][0] +
            lr * 128 + (((kk * 4 + hi) ^ (lr & 7)) << 4));
#pragma unroll
      for (int ni = 0; ni < 3; ++ni) {
        const int row = wc * 48 + ni * 16 + lr;
        bfr[ni] = *(const bf16x8*)((char*)&Bs[buf][0] +
                   row * 128 + (((kk * 4 + hi) ^ (row & 7)) << 4));
      }
#pragma unroll
      for (int ni = 0; ni < 3; ++ni)
        acc[ni] = __builtin_amdgcn_mfma_f32_16x16x32_bf16(
            af, bfr[ni], acc[ni], 0, 0, 0);
    }
  };

  float4 a0;
  ALOAD(0, a0); BSTAGE(0, 0); AWRITE(0, a0);
  __syncthreads();
#pragma unroll
  for (int t = 0; t < 16; ++t) {
    const int cur = t & 1;
    float4 an;
    if (t < 15) { ALOAD(t + 1, an); BSTAGE(t + 1, cur ^ 1); }
    COMPUTE(cur);
    if (t < 15) AWRITE(cur ^ 1, an);
    __syncthreads();
  }

#pragma unroll
  for (int ni = 0; ni < 3; ++ni)
#pragma unroll
    for (int r = 0; r < 4; ++r) {
      const int row = m0 + hi * 4 + r;
      const int col = wc * 48 + ni * 16 + lr;
      Y[(size_t)row * KTAB + col] = __float2bfloat16(acc[ni][r]);
    }
}

// ---------------- G2: out = Y @ Tb^T + bias, BK=64, dbuf, swizzled -------
// grid (8, 64), 256 threads (2x2 waves, each 32x64 = acc[2][4]).
__global__ __launch_bounds__(256)
void gemm_out(const __hip_bfloat16* __restrict__ Y,   // [4096][192]
              const __hip_bfloat16* __restrict__ Tb,  // [1024][192]
              float* __restrict__ out,                // [4096][1024]
              const float* __restrict__ bias) {       // [1024]
  __shared__ __align__(16) __hip_bfloat16 As[2][64 * 64];
  __shared__ __align__(16) __hip_bfloat16 Bs[2][128 * 64];
  const int tid  = threadIdx.x;
  const int lane = tid & 63;
  const int wave = tid >> 6;
  const int wr = wave >> 1;
  const int wc = wave & 1;
  const int m0 = blockIdx.y * 64;
  const int n0 = blockIdx.x * 128;
  const int lr = lane & 15;
  const int hi = lane >> 4;

  f32x4 acc[2][4] = {};

  auto ASTAGE = [&](int t, int buf) {
#pragma unroll
    for (int q = 0; q < 2; ++q) {
      const int f = q * 256 + tid;           // 512 chunks (64 rows x 8)
      const int r = f >> 3, g = f & 7;
      gload_lds16(Y + (size_t)(m0 + r) * KTAB + t * 64 + ((g ^ (r & 7)) * 8),
                  (char*)&As[buf][0] + (size_t)f * 16);
    }
  };
  auto BSTAGE = [&](int t, int buf) {
#pragma unroll
    for (int q = 0; q < 4; ++q) {
      const int f = q * 256 + tid;           // 1024 chunks (128 rows x 8)
      const int r = f >> 3, g = f & 7;
      gload_lds16(Tb + (size_t)(n0 + r) * KTAB + t * 64 + ((g ^ (r & 7)) * 8),
                  (char*)&Bs[buf][0] + (size_t)f * 16);
    }
  };
  auto COMPUTE = [&](int buf) {
#pragma unroll
    for (int kk = 0; kk < 2; ++kk) {
      bf16x8 af[2], bfr[4];
#pragma unroll
      for (int mi = 0; mi < 2; ++mi) {
        const int row = wr * 32 + mi * 16 + lr;
        af[mi] = *(const bf16x8*)((char*)&As[buf][0] +
                  row * 128 + (((kk * 4 + hi) ^ (row & 7)) << 4));
      }
#pragma unroll
      for (int ni = 0; ni < 4; ++ni) {
        const int row = wc * 64 + ni * 16 + lr;
        bfr[ni] = *(const bf16x8*)((char*)&Bs[buf][0] +
                   row * 128 + (((kk * 4 + hi) ^ (row & 7)) << 4));
      }
#pragma unroll
      for (int mi = 0; mi < 2; ++mi)
#pragma unroll
        for (int ni = 0; ni < 4; ++ni)
          acc[mi][ni] = __builtin_amdgcn_mfma_f32_16x16x32_bf16(
              af[mi], bfr[ni], acc[mi][ni], 0, 0, 0);
    }
  };

  ASTAGE(0, 0); BSTAGE(0, 0);
  __syncthreads();
#pragma unroll
  for (int t = 0; t < 3; ++t) {
    const int cur = t & 1;
    if (t < 2) { ASTAGE(t + 1, cur ^ 1); BSTAGE(t + 1, cur ^ 1); }
    COMPUTE(cur);
    __syncthreads();
  }

#pragma unroll
  for (int mi = 0; mi < 2; ++mi)
#pragma unroll
    for (int ni = 0; ni < 4; ++ni)
#pragma unroll
      for (int r = 0; r < 4; ++r) {
        const int row = m0 + wr * 32 + mi * 16 + hi * 4 + r;
        const int col = n0 + wc * 64 + ni * 16 + lr;
        out[(size_t)row * OUT_DIM + col] = acc[mi][ni][r] + bias[col];
      }
}

extern "C" void kernel_launch(void* const* d_in, const int* in_sizes, int n_in,
                              void* d_out, int out_size, void* d_ws, size_t ws_size,
                              hipStream_t stream) {
  const float* x     = (const float*)d_in[0];   // [4096][1024] f32
  const float* omega = (const float*)d_in[1];   // [96][3]
  const float* phi   = (const float*)d_in[2];   // [96]
  const float* alpha = (const float*)d_in[3];   // [192]
  const float* bias  = (const float*)d_in[4];   // [1024]
  float* out = (float*)d_out;                   // [4096][1024] f32
  (void)in_sizes; (void)n_in; (void)out_size; (void)ws_size;

  char* ws = (char*)d_ws;
  __hip_bfloat16* Y   = (__hip_bfloat16*)(ws);                // 1.5 MiB
  __hip_bfloat16* TaT = (__hip_bfloat16*)(ws + 1572864);      // 384 KiB
  __hip_bfloat16* Tb  = (__hip_bfloat16*)(ws + 1966080);      // 384 KiB

  build_tables<<<dim3(NBANDS, 4), dim3(256), 0, stream>>>(omega, phi, alpha, TaT, Tb);
  gemm_xta<<<dim3(MX / 16), dim3(256), 0, stream>>>(x, TaT, Y);
  gemm_out<<<dim3(OUT_DIM / 128, MX / 64), dim3(256), 0, stream>>>(Y, Tb, out, bias);
}

// Round 6
// 99.620 us; speedup vs baseline: 1.0119x; 1.0119x over previous
//
#include <hip/hip_runtime.h>
#include <hip/hip_bf16.h>
#include <math.h>

// FourierWeightLinear: out = x @ W + bias, W = Ta(1024x192) . Tb(1024x192)^T.
// Associativity: out = (x @ Ta) @ Tb^T  -- never materialize W.
//   u = ox*iv + oz*0.5 + phi;  iv(i)=jv(i)=(i+1)/1025 (exact f32 match to ref)
//   TaT[2t][i]=P, TaT[2t+1][i]=Q;  Tb[j][2t]=cos(oy*jv), Tb[j][2t+1]=sin(oy*jv)
// G1: Y[4096][192] = x @ Ta  (BM=16 -> 256 blocks, fused f32->bf16 cvt)
// G2: out = Y @ Tb^T + bias  (K=192, BK=64)
// Pipelining: T4 counted-vmcnt (never drain vmcnt to 0 in the loop):
//   issue stage(t+1) ; s_waitcnt vmcnt(7) lgkmcnt(0) ; s_barrier ; MFMA ;
//   s_waitcnt lgkmcnt(0) ; s_barrier    (WAR barrier, loads stay in flight)
// LDS XOR-swizzle (chunk ^= row&7) on both stage & read sides (rule 21).

#define IN_DIM   1024
#define OUT_DIM  1024
#define NBANDS   96
#define KTAB     192
#define MX       4096
#define SCALE_W  0.03125f

typedef __bf16 bf16x8 __attribute__((ext_vector_type(8)));
typedef float  f32x4  __attribute__((ext_vector_type(4)));

#define AS1 __attribute__((address_space(1)))
#define AS3 __attribute__((address_space(3)))

__device__ __forceinline__ void gload_lds16(const void* g, void* l) {
  __builtin_amdgcn_global_load_lds((AS1 void*)(g), (AS3 void*)(l), 16, 0, 0);
}

__device__ __forceinline__ unsigned short bf16bits(float f) {
  __hip_bfloat16 b = __float2bfloat16(f);
  return *(unsigned short*)&b;
}

// counted stage-wait: leave the N newest vmem ops in flight; drain LDS ops.
__device__ __forceinline__ void wait_vm_lgkm(int n) {
  switch (n) {   // folded to one case under full unroll
    case 7: asm volatile("s_waitcnt vmcnt(7) lgkmcnt(0)" ::: "memory"); break;
    case 6: asm volatile("s_waitcnt vmcnt(6) lgkmcnt(0)" ::: "memory"); break;
    default: asm volatile("s_waitcnt vmcnt(0) lgkmcnt(0)" ::: "memory"); break;
  }
}
__device__ __forceinline__ void lgkm0_barrier() {
  asm volatile("s_waitcnt lgkmcnt(0)" ::: "memory");
  __builtin_amdgcn_s_barrier();
}

// ---------------- tables: 384 blocks (96 bands x 4 row-chunks) -----------
__global__ void build_tables(const float* __restrict__ omega,  // [96][3]
                             const float* __restrict__ phi,    // [96]
                             const float* __restrict__ alpha,  // [192]
                             __hip_bfloat16* __restrict__ TaT, // [192][1024]
                             __hip_bfloat16* __restrict__ Tb) {// [1024][192]
  const int t = blockIdx.x;
  const int i = blockIdx.y * 256 + threadIdx.x;     // 0..1023
  const float ox = omega[3 * t], oy = omega[3 * t + 1], oz = omega[3 * t + 2];
  const float uc = oz * 0.5f + phi[t];
  const float as_ = alpha[t], ac = alpha[NBANDS + t];
  const float coord = (float)(i + 1) / 1025.0f;     // == pos coords exactly
  float su, cu;
  sincosf(ox * coord + uc, &su, &cu);
  TaT[(size_t)(2 * t) * IN_DIM + i]     = __float2bfloat16(SCALE_W * (as_ * su + ac * cu));
  TaT[(size_t)(2 * t + 1) * IN_DIM + i] = __float2bfloat16(SCALE_W * (as_ * cu - ac * su));
  float sv, cv;
  sincosf(oy * coord, &sv, &cv);
  Tb[(size_t)i * KTAB + 2 * t]     = __float2bfloat16(cv);
  Tb[(size_t)i * KTAB + 2 * t + 1] = __float2bfloat16(sv);
}

// ---------------- G1: Y = x @ Ta, BM=16, BK=64, counted-vmcnt pipeline ---
// grid (256), 256 threads = 4 waves; wave w -> cols 48w..48w+47, acc[3].
__global__ __launch_bounds__(256)
void gemm_xta(const float* __restrict__ X,             // [4096][1024] f32
              const __hip_bfloat16* __restrict__ TaT,  // [192][1024]
              __hip_bfloat16* __restrict__ Y) {        // [4096][192]
  __shared__ __align__(16) __hip_bfloat16 As[2][16 * 64];
  __shared__ __align__(16) __hip_bfloat16 Bs[2][192 * 64];
  const int tid  = threadIdx.x;
  const int lane = tid & 63;
  const int wc   = tid >> 6;
  const int m0   = blockIdx.x * 16;
  const int lr = lane & 15;
  const int hi = lane >> 4;          // 0..3 -> k 16B-chunk within 32-elem half

  const float* xbase = X + (size_t)m0 * IN_DIM;

  f32x4 acc[3] = {};

  auto ALOAD = [&](int t, float4& a) {
    const int r = tid >> 4, c4 = tid & 15;   // 16 float4 per 64-f32 row
    a = *(const float4*)(xbase + (size_t)r * IN_DIM + t * 64 + c4 * 4);
  };
  auto AWRITE = [&](int buf, const float4& a) {
    const int r = tid >> 4, c4 = tid & 15;   // c4 = 8B-chunk index
    ushort4 o;
    o.x = bf16bits(a.x); o.y = bf16bits(a.y);
    o.z = bf16bits(a.z); o.w = bf16bits(a.w);
    const int byte = r * 128 + ((((c4 >> 1) ^ (r & 7)) << 4) | ((c4 & 1) << 3));
    *(ushort4*)((char*)&As[buf][0] + byte) = o;
  };
  auto BSTAGE = [&](int t, int buf) {
#pragma unroll
    for (int q = 0; q < 6; ++q) {
      const int f = q * 256 + tid;           // 1536 16B chunks, LDS linear
      const int r = f >> 3, g = f & 7;
      gload_lds16(TaT + (size_t)r * IN_DIM + t * 64 + ((g ^ (r & 7)) * 8),
                  (char*)&Bs[buf][0] + (size_t)f * 16);
    }
  };
  auto COMPUTE = [&](int buf) {
#pragma unroll
    for (int kk = 0; kk < 2; ++kk) {
      bf16x8 af, bfr[3];
      af = *(const bf16x8*)((char*)&As[buf][0] +
            lr * 128 + (((kk * 4 + hi) ^ (lr & 7)) << 4));
#pragma unroll
      for (int ni = 0; ni < 3; ++ni) {
        const int row = wc * 48 + ni * 16 + lr;
        bfr[ni] = *(const bf16x8*)((char*)&Bs[buf][0] +
                   row * 128 + (((kk * 4 + hi) ^ (row & 7)) << 4));
      }
#pragma unroll
      for (int ni = 0; ni < 3; ++ni)
        acc[ni] = __builtin_amdgcn_mfma_f32_16x16x32_bf16(
            af, bfr[ni], acc[ni], 0, 0, 0);
    }
  };

  // prologue: tile 0 staged, tiles 0 & 1 A-loaded (depth-2 A prefetch)
  float4 areg[2];
  ALOAD(0, areg[0]);
  BSTAGE(0, 0);
  ALOAD(1, areg[1]);
  AWRITE(0, areg[0]);                // auto-waits areg[0] (one-time stall)

#pragma unroll
  for (int t = 0; t < 16; ++t) {
    const int cur = t & 1;
    if (t < 15) BSTAGE(t + 1, cur ^ 1);         // 6 vmem
    if (t < 14) ALOAD(t + 2, areg[t & 1]);      // 1 vmem
    wait_vm_lgkm(t < 14 ? 7 : (t < 15 ? 6 : 0)); // stage t done; t+1 in flight
    __builtin_amdgcn_s_barrier();
    COMPUTE(cur);
    if (t < 15) AWRITE(cur ^ 1, areg[(t + 1) & 1]);
    lgkm0_barrier();                 // WAR barrier: no vmcnt drain
  }

#pragma unroll
  for (int ni = 0; ni < 3; ++ni)
#pragma unroll
    for (int r = 0; r < 4; ++r) {
      const int row = m0 + hi * 4 + r;
      const int col = wc * 48 + ni * 16 + lr;
      Y[(size_t)row * KTAB + col] = __float2bfloat16(acc[ni][r]);
    }
}

// ---------------- G2: out = Y @ Tb^T + bias, BK=64, counted-vmcnt --------
// grid (8, 64), 256 threads (2x2 waves, each 32x64 = acc[2][4]).
__global__ __launch_bounds__(256)
void gemm_out(const __hip_bfloat16* __restrict__ Y,   // [4096][192]
              const __hip_bfloat16* __restrict__ Tb,  // [1024][192]
              float* __restrict__ out,                // [4096][1024]
              const float* __restrict__ bias) {       // [1024]
  __shared__ __align__(16) __hip_bfloat16 As[2][64 * 64];
  __shared__ __align__(16) __hip_bfloat16 Bs[2][128 * 64];
  const int tid  = threadIdx.x;
  const int lane = tid & 63;
  const int wave = tid >> 6;
  const int wr = wave >> 1;
  const int wc = wave & 1;
  const int m0 = blockIdx.y * 64;
  const int n0 = blockIdx.x * 128;
  const int lr = lane & 15;
  const int hi = lane >> 4;

  f32x4 acc[2][4] = {};

  auto ASTAGE = [&](int t, int buf) {
#pragma unroll
    for (int q = 0; q < 2; ++q) {
      const int f = q * 256 + tid;           // 512 chunks (64 rows x 8)
      const int r = f >> 3, g = f & 7;
      gload_lds16(Y + (size_t)(m0 + r) * KTAB + t * 64 + ((g ^ (r & 7)) * 8),
                  (char*)&As[buf][0] + (size_t)f * 16);
    }
  };
  auto BSTAGE = [&](int t, int buf) {
#pragma unroll
    for (int q = 0; q < 4; ++q) {
      const int f = q * 256 + tid;           // 1024 chunks (128 rows x 8)
      const int r = f >> 3, g = f & 7;
      gload_lds16(Tb + (size_t)(n0 + r) * KTAB + t * 64 + ((g ^ (r & 7)) * 8),
                  (char*)&Bs[buf][0] + (size_t)f * 16);
    }
  };
  auto COMPUTE = [&](int buf) {
#pragma unroll
    for (int kk = 0; kk < 2; ++kk) {
      bf16x8 af[2], bfr[4];
#pragma unroll
      for (int mi = 0; mi < 2; ++mi) {
        const int row = wr * 32 + mi * 16 + lr;
        af[mi] = *(const bf16x8*)((char*)&As[buf][0] +
                  row * 128 + (((kk * 4 + hi) ^ (row & 7)) << 4));
      }
#pragma unroll
      for (int ni = 0; ni < 4; ++ni) {
        const int row = wc * 64 + ni * 16 + lr;
        bfr[ni] = *(const bf16x8*)((char*)&Bs[buf][0] +
                   row * 128 + (((kk * 4 + hi) ^ (row & 7)) << 4));
      }
#pragma unroll
      for (int mi = 0; mi < 2; ++mi)
#pragma unroll
        for (int ni = 0; ni < 4; ++ni)
          acc[mi][ni] = __builtin_amdgcn_mfma_f32_16x16x32_bf16(
              af[mi], bfr[ni], acc[mi][ni], 0, 0, 0);
    }
  };

  ASTAGE(0, 0); BSTAGE(0, 0);
#pragma unroll
  for (int t = 0; t < 3; ++t) {
    const int cur = t & 1;
    if (t < 2) { ASTAGE(t + 1, cur ^ 1); BSTAGE(t + 1, cur ^ 1); }  // 6 vmem
    wait_vm_lgkm(t < 2 ? 6 : 0);
    __builtin_amdgcn_s_barrier();
    COMPUTE(cur);
    lgkm0_barrier();                 // WAR barrier: no vmcnt drain
  }

#pragma unroll
  for (int mi = 0; mi < 2; ++mi)
#pragma unroll
    for (int ni = 0; ni < 4; ++ni)
#pragma unroll
      for (int r = 0; r < 4; ++r) {
        const int row = m0 + wr * 32 + mi * 16 + hi * 4 + r;
        const int col = n0 + wc * 64 + ni * 16 + lr;
        out[(size_t)row * OUT_DIM + col] = acc[mi][ni][r] + bias[col];
      }
}

extern "C" void kernel_launch(void* const* d_in, const int* in_sizes, int n_in,
                              void* d_out, int out_size, void* d_ws, size_t ws_size,
                              hipStream_t stream) {
  const float* x     = (const float*)d_in[0];   // [4096][1024] f32
  const float* omega = (const float*)d_in[1];   // [96][3]
  const float* phi   = (const float*)d_in[2];   // [96]
  const float* alpha = (const float*)d_in[3];   // [192]
  const float* bias  = (const float*)d_in[4];   // [1024]
  float* out = (float*)d_out;                   // [4096][1024] f32
  (void)in_sizes; (void)n_in; (void)out_size; (void)ws_size;

  char* ws = (char*)d_ws;
  __hip_bfloat16* Y   = (__hip_bfloat16*)(ws);                // 1.5 MiB
  __hip_bfloat16* TaT = (__hip_bfloat16*)(ws + 1572864);      // 384 KiB
  __hip_bfloat16* Tb  = (__hip_bfloat16*)(ws + 1966080);      // 384 KiB

  build_tables<<<dim3(NBANDS, 4), dim3(256), 0, stream>>>(omega, phi, alpha, TaT, Tb);
  gemm_xta<<<dim3(MX / 16), dim3(256), 0, stream>>>(x, TaT, Y);
  gemm_out<<<dim3(OUT_DIM / 128, MX / 64), dim3(256), 0, stream>>>(Y, Tb, out, bias);
}